// Round 1
// baseline (686.949 us; speedup 1.0000x reference)
//
#include <hip/hip_runtime.h>
#include <math.h>

constexpr int kNodes = 50000;
constexpr int kDim   = 128;
constexpr int kEdges = 600000;
constexpr float kAlpha = 0.2f;

// ws layout (floats): [0]=global max, [1]=global sumexp, [4..4+kEdges)=scores
__device__ __forceinline__ void atomicMaxF(float* addr, float val) {
    // standard signed/unsigned split trick for IEEE-754 ordering
    if (val >= 0.0f) atomicMax((int*)addr, __float_as_int(val));
    else             atomicMin((unsigned int*)addr, __float_as_uint(val));
}

__global__ void init_kernel(float* ws) {
    if (threadIdx.x == 0) { ws[0] = -INFINITY; ws[1] = 0.0f; }
}

__global__ void copy_kernel(const float4* __restrict__ src, float4* __restrict__ dst, int n4) {
    for (int i = blockIdx.x * blockDim.x + threadIdx.x; i < n4; i += gridDim.x * blockDim.x)
        dst[i] = src[i];
}

// One wave (64 lanes) per edge: lane i holds float2 => 128 dims.
__global__ void scores_max_kernel(const float* __restrict__ emb,
                                  const int* __restrict__ rel,
                                  float* __restrict__ scores,
                                  float* __restrict__ gmax) {
    const int lane = threadIdx.x & 63;
    const int wave = threadIdx.x >> 6;
    const int wavesPerBlock = blockDim.x >> 6;
    const int gw = blockIdx.x * wavesPerBlock + wave;
    const int nw = gridDim.x * wavesPerBlock;

    float lmax = -INFINITY;
    for (int e = gw; e < kEdges; e += nw) {
        const int s = rel[2 * e];
        const int d = rel[2 * e + 1];
        const float2 a = ((const float2*)(emb + (long long)s * kDim))[lane];
        const float2 b = ((const float2*)(emb + (long long)d * kDim))[lane];
        float p = a.x * b.x + a.y * b.y;
        #pragma unroll
        for (int off = 32; off > 0; off >>= 1) p += __shfl_down(p, off);
        if (lane == 0) {
            const float sc = p > 0.0f ? p : kAlpha * p;
            scores[e] = sc;
            lmax = fmaxf(lmax, sc);
        }
    }
    __shared__ float red[256];
    red[threadIdx.x] = lmax;
    __syncthreads();
    for (int s = blockDim.x >> 1; s > 0; s >>= 1) {
        if ((int)threadIdx.x < s) red[threadIdx.x] = fmaxf(red[threadIdx.x], red[threadIdx.x + s]);
        __syncthreads();
    }
    if (threadIdx.x == 0) atomicMaxF(gmax, red[0]);
}

__global__ void sumexp_kernel(const float* __restrict__ scores,
                              const float* __restrict__ gmax,
                              float* __restrict__ gsum) {
    const float m = *gmax;
    float acc = 0.0f;
    for (int i = blockIdx.x * blockDim.x + threadIdx.x; i < kEdges; i += gridDim.x * blockDim.x)
        acc += expf(scores[i] - m);
    __shared__ float red[256];
    red[threadIdx.x] = acc;
    __syncthreads();
    for (int s = blockDim.x >> 1; s > 0; s >>= 1) {
        if ((int)threadIdx.x < s) red[threadIdx.x] += red[threadIdx.x + s];
        __syncthreads();
    }
    if (threadIdx.x == 0) atomicAdd(gsum, red[0]);
}

// One wave per edge: att * emb[dst] scatter-added into out[src].
__global__ void scatter_kernel(const float* __restrict__ emb,
                               const int* __restrict__ rel,
                               const float* __restrict__ scores,
                               const float* __restrict__ gmax,
                               const float* __restrict__ gsum,
                               float* __restrict__ out) {
    const int lane = threadIdx.x & 63;
    const int wave = threadIdx.x >> 6;
    const int wavesPerBlock = blockDim.x >> 6;
    const int gw = blockIdx.x * wavesPerBlock + wave;
    const int nw = gridDim.x * wavesPerBlock;

    const float m = *gmax;
    const float invs = 1.0f / *gsum;

    for (int e = gw; e < kEdges; e += nw) {
        const int s = rel[2 * e];
        const int d = rel[2 * e + 1];
        const float att = expf(scores[e] - m) * invs;
        const float2 b = ((const float2*)(emb + (long long)d * kDim))[lane];
        float* op = out + (long long)s * kDim + 2 * lane;
        atomicAdd(op,     b.x * att);
        atomicAdd(op + 1, b.y * att);
    }
}

extern "C" void kernel_launch(void* const* d_in, const int* in_sizes, int n_in,
                              void* d_out, int out_size, void* d_ws, size_t ws_size,
                              hipStream_t stream) {
    const float* emb = (const float*)d_in[0];
    const int*   rel = (const int*)d_in[1];
    float* out = (float*)d_out;
    float* wsf = (float*)d_ws;
    float* gmax   = wsf;
    float* gsum   = wsf + 1;
    float* scores = wsf + 4;

    hipLaunchKernelGGL(init_kernel, dim3(1), dim3(64), 0, stream, wsf);
    const int n4 = kNodes * kDim / 4;
    hipLaunchKernelGGL(copy_kernel, dim3(1024), dim3(256), 0, stream,
                       (const float4*)emb, (float4*)out, n4);
    hipLaunchKernelGGL(scores_max_kernel, dim3(2048), dim3(256), 0, stream,
                       emb, rel, scores, gmax);
    hipLaunchKernelGGL(sumexp_kernel, dim3(1024), dim3(256), 0, stream,
                       scores, gmax, gsum);
    hipLaunchKernelGGL(scatter_kernel, dim3(2048), dim3(256), 0, stream,
                       emb, rel, scores, gmax, gsum, out);
}

// Round 2
// 335.709 us; speedup vs baseline: 2.0463x; 2.0463x over previous
//
#include <hip/hip_runtime.h>
#include <math.h>

constexpr int kNodes = 50000;
constexpr int kDim   = 128;
constexpr int kEdges = 600000;
constexpr float kAlpha = 0.2f;

// scan geometry
constexpr int kScanChunk = 1024;                                // elems per scan block
constexpr int kScanBlocks = (kNodes + kScanChunk - 1) / kScanChunk; // 49

// ws layout (4-byte units):
// [0]=gmax [1]=gsum [2..4)=pad
// [4)                scores   : kEdges floats
// [+kEdges)          counts   : kNodes ints
// [+kNodes)          offsets  : kNodes ints
// [+kNodes)          cursor   : kNodes ints
// [+kNodes)          csr      : kEdges ints
// [+kEdges)          blocksum : 64 ints
constexpr int kOffScores   = 4;
constexpr int kOffCounts   = kOffScores + kEdges;
constexpr int kOffOffsets  = kOffCounts + kNodes;
constexpr int kOffCursor   = kOffOffsets + kNodes;
constexpr int kOffCsr      = kOffCursor + kNodes;
constexpr int kOffBlockSum = kOffCsr + kEdges;

__device__ __forceinline__ void atomicMaxF(float* addr, float val) {
    if (val >= 0.0f) atomicMax((int*)addr, __float_as_int(val));
    else             atomicMin((unsigned int*)addr, __float_as_uint(val));
}

__global__ void init_kernel(float* wsf, int* counts) {
    int i = blockIdx.x * blockDim.x + threadIdx.x;
    if (i == 0) { wsf[0] = -INFINITY; wsf[1] = 0.0f; }
    for (; i < kNodes; i += gridDim.x * blockDim.x) counts[i] = 0;
}

// One wave per edge: score + leaky relu; lane0 bumps histogram + block max.
__global__ void scores_max_count_kernel(const float* __restrict__ emb,
                                        const int* __restrict__ rel,
                                        float* __restrict__ scores,
                                        int* __restrict__ counts,
                                        float* __restrict__ gmax) {
    const int lane = threadIdx.x & 63;
    const int wave = threadIdx.x >> 6;
    const int gw = blockIdx.x * (blockDim.x >> 6) + wave;
    const int nw = gridDim.x * (blockDim.x >> 6);

    float lmax = -INFINITY;
    for (int e = gw; e < kEdges; e += nw) {
        const int s = rel[2 * e];
        const int d = rel[2 * e + 1];
        const float2 a = ((const float2*)(emb + (long long)s * kDim))[lane];
        const float2 b = ((const float2*)(emb + (long long)d * kDim))[lane];
        float p = a.x * b.x + a.y * b.y;
        #pragma unroll
        for (int off = 32; off > 0; off >>= 1) p += __shfl_down(p, off);
        if (lane == 0) {
            const float sc = p > 0.0f ? p : kAlpha * p;
            scores[e] = sc;
            atomicAdd(&counts[s], 1);
            lmax = fmaxf(lmax, sc);
        }
    }
    __shared__ float red[256];
    red[threadIdx.x] = lmax;
    __syncthreads();
    for (int s = blockDim.x >> 1; s > 0; s >>= 1) {
        if ((int)threadIdx.x < s) red[threadIdx.x] = fmaxf(red[threadIdx.x], red[threadIdx.x + s]);
        __syncthreads();
    }
    if (threadIdx.x == 0) atomicMaxF(gmax, red[0]);
}

__global__ void sumexp_kernel(const float* __restrict__ scores,
                              const float* __restrict__ gmax,
                              float* __restrict__ gsum) {
    const float m = *gmax;
    float acc = 0.0f;
    for (int i = blockIdx.x * blockDim.x + threadIdx.x; i < kEdges; i += gridDim.x * blockDim.x)
        acc += expf(scores[i] - m);
    __shared__ float red[256];
    red[threadIdx.x] = acc;
    __syncthreads();
    for (int s = blockDim.x >> 1; s > 0; s >>= 1) {
        if ((int)threadIdx.x < s) red[threadIdx.x] += red[threadIdx.x + s];
        __syncthreads();
    }
    if (threadIdx.x == 0) atomicAdd(gsum, red[0]);
}

// Scan stage A: per-1024-chunk sums of counts.
__global__ void scanA_kernel(const int* __restrict__ counts, int* __restrict__ blocksum) {
    const int base = blockIdx.x * kScanChunk;
    int acc = 0;
    #pragma unroll
    for (int j = 0; j < 4; ++j) {
        const int i = base + 4 * (int)threadIdx.x + j;
        if (i < kNodes) acc += counts[i];
    }
    __shared__ int red[256];
    red[threadIdx.x] = acc;
    __syncthreads();
    for (int s = blockDim.x >> 1; s > 0; s >>= 1) {
        if ((int)threadIdx.x < s) red[threadIdx.x] += red[threadIdx.x + s];
        __syncthreads();
    }
    if (threadIdx.x == 0) blocksum[blockIdx.x] = red[0];
}

// Scan stage B: exclusive scan of the 49 chunk sums (single tiny block).
__global__ void scanB_kernel(int* __restrict__ blocksum) {
    __shared__ int lds[kScanBlocks];
    if ((int)threadIdx.x < kScanBlocks) lds[threadIdx.x] = blocksum[threadIdx.x];
    __syncthreads();
    if (threadIdx.x == 0) {
        int run = 0;
        for (int i = 0; i < kScanBlocks; ++i) { int t = lds[i]; lds[i] = run; run += t; }
    }
    __syncthreads();
    if ((int)threadIdx.x < kScanBlocks) blocksum[threadIdx.x] = lds[threadIdx.x];
}

// Scan stage C: per-chunk exclusive scan + chunk offset -> offsets & cursor.
__global__ void scanC_kernel(const int* __restrict__ counts,
                             const int* __restrict__ blocksum,
                             int* __restrict__ offsets,
                             int* __restrict__ cursor) {
    const int base = blockIdx.x * kScanChunk;
    const int lane = threadIdx.x & 63;
    const int wave = threadIdx.x >> 6;
    int c[4];
    int sum4 = 0;
    #pragma unroll
    for (int j = 0; j < 4; ++j) {
        const int i = base + 4 * (int)threadIdx.x + j;
        c[j] = (i < kNodes) ? counts[i] : 0;
        sum4 += c[j];
    }
    // wave-inclusive scan of thread sums
    int incl = sum4;
    #pragma unroll
    for (int off = 1; off < 64; off <<= 1) {
        int v = __shfl_up(incl, off);
        if (lane >= off) incl += v;
    }
    __shared__ int waveSum[4];
    __shared__ int waveOff[4];
    if (lane == 63) waveSum[wave] = incl;
    __syncthreads();
    if (threadIdx.x == 0) {
        int run = 0;
        for (int w = 0; w < 4; ++w) { int t = waveSum[w]; waveOff[w] = run; run += t; }
    }
    __syncthreads();
    int excl = blocksum[blockIdx.x] + waveOff[wave] + (incl - sum4);
    #pragma unroll
    for (int j = 0; j < 4; ++j) {
        const int i = base + 4 * (int)threadIdx.x + j;
        if (i < kNodes) { offsets[i] = excl; cursor[i] = excl; }
        excl += c[j];
    }
}

__global__ void fill_kernel(const int* __restrict__ rel,
                            int* __restrict__ cursor,
                            int* __restrict__ csr) {
    for (int e = blockIdx.x * blockDim.x + threadIdx.x; e < kEdges; e += gridDim.x * blockDim.x) {
        const int s = rel[2 * e];
        const int pos = atomicAdd(&cursor[s], 1);
        csr[pos] = e;
    }
}

// One wave per node: out[n] = emb[n] + sum_e att(e) * emb[dst(e)]
__global__ void gather_kernel(const float* __restrict__ emb,
                              const int* __restrict__ rel,
                              const float* __restrict__ scores,
                              const int* __restrict__ offsets,
                              const int* __restrict__ counts,
                              const int* __restrict__ csr,
                              const float* __restrict__ gmax,
                              const float* __restrict__ gsum,
                              float* __restrict__ out) {
    const int lane = threadIdx.x & 63;
    const int wave = threadIdx.x >> 6;
    const int node = blockIdx.x * (blockDim.x >> 6) + wave;
    if (node >= kNodes) return;

    const float m = *gmax;
    const float invs = 1.0f / *gsum;

    float2 acc = ((const float2*)(emb + (long long)node * kDim))[lane];  // residual
    const int off = offsets[node];
    const int cnt = counts[node];
    for (int k = off; k < off + cnt; ++k) {
        const int e = csr[k];
        const int d = rel[2 * e + 1];
        const float att = expf(scores[e] - m) * invs;
        const float2 b = ((const float2*)(emb + (long long)d * kDim))[lane];
        acc.x += att * b.x;
        acc.y += att * b.y;
    }
    ((float2*)(out + (long long)node * kDim))[lane] = acc;
}

extern "C" void kernel_launch(void* const* d_in, const int* in_sizes, int n_in,
                              void* d_out, int out_size, void* d_ws, size_t ws_size,
                              hipStream_t stream) {
    const float* emb = (const float*)d_in[0];
    const int*   rel = (const int*)d_in[1];
    float* out = (float*)d_out;
    float* wsf = (float*)d_ws;
    int*   wsi = (int*)d_ws;

    float* gmax     = wsf;
    float* gsum     = wsf + 1;
    float* scores   = wsf + kOffScores;
    int*   counts   = wsi + kOffCounts;
    int*   offsets  = wsi + kOffOffsets;
    int*   cursor   = wsi + kOffCursor;
    int*   csr      = wsi + kOffCsr;
    int*   blocksum = wsi + kOffBlockSum;

    hipLaunchKernelGGL(init_kernel, dim3(196), dim3(256), 0, stream, wsf, counts);
    hipLaunchKernelGGL(scores_max_count_kernel, dim3(2048), dim3(256), 0, stream,
                       emb, rel, scores, counts, gmax);
    hipLaunchKernelGGL(sumexp_kernel, dim3(1024), dim3(256), 0, stream,
                       scores, gmax, gsum);
    hipLaunchKernelGGL(scanA_kernel, dim3(kScanBlocks), dim3(256), 0, stream, counts, blocksum);
    hipLaunchKernelGGL(scanB_kernel, dim3(1), dim3(64), 0, stream, blocksum);
    hipLaunchKernelGGL(scanC_kernel, dim3(kScanBlocks), dim3(256), 0, stream,
                       counts, blocksum, offsets, cursor);
    hipLaunchKernelGGL(fill_kernel, dim3(1024), dim3(256), 0, stream, rel, cursor, csr);
    hipLaunchKernelGGL(gather_kernel, dim3((kNodes + 3) / 4), dim3(256), 0, stream,
                       emb, rel, scores, offsets, counts, csr, gmax, gsum, out);
}

// Round 3
// 258.820 us; speedup vs baseline: 2.6542x; 1.2971x over previous
//
#include <hip/hip_runtime.h>
#include <math.h>

constexpr int kNodes = 50000;
constexpr int kDim   = 128;
constexpr int kEdges = 600000;
constexpr float kAlpha = 0.2f;

constexpr int kScanChunk  = 1024;
constexpr int kScanBlocks = (kNodes + kScanChunk - 1) / kScanChunk; // 49

// ws layout (4-byte units):
constexpr int kOffScores   = 4;
constexpr int kOffCounts   = kOffScores + kEdges;
constexpr int kOffOffsets  = kOffCounts + kNodes;
constexpr int kOffCursor   = kOffOffsets + kNodes;
constexpr int kOffMeta     = kOffCursor + kNodes;      // float2 per edge (dst,w) — even offset ✓
constexpr int kOffBlockSum = kOffMeta + 2 * kEdges;

__device__ __forceinline__ void atomicMaxF(float* addr, float val) {
    if (val >= 0.0f) atomicMax((int*)addr, __float_as_int(val));
    else             atomicMin((unsigned int*)addr, __float_as_uint(val));
}

__global__ void init_kernel(float* wsf, int* counts) {
    int i = blockIdx.x * blockDim.x + threadIdx.x;
    if (i == 0) { wsf[0] = -INFINITY; wsf[1] = 0.0f; }
    for (; i < kNodes; i += gridDim.x * blockDim.x) counts[i] = 0;
}

// 16 lanes per edge, 2 edges per subwave iteration (unroll x2).
__global__ void scores_max_count_kernel(const float4* __restrict__ emb4,
                                        const int2* __restrict__ rel2,
                                        float* __restrict__ scores,
                                        int* __restrict__ counts,
                                        float* __restrict__ gmax) {
    const int g    = threadIdx.x & 15;
    const int swid = (blockIdx.x * blockDim.x + threadIdx.x) >> 4;
    const int nsw  = (gridDim.x * blockDim.x) >> 4;

    float lmax = -INFINITY;
    for (int e0 = swid; e0 < kEdges; e0 += 2 * nsw) {
        const int e1 = e0 + nsw;
        const bool has1 = (e1 < kEdges);
        const int2 sd0 = rel2[e0];
        const int2 sd1 = has1 ? rel2[e1] : sd0;

        const long long sa0 = (long long)sd0.x * 32, da0 = (long long)sd0.y * 32;
        const long long sa1 = (long long)sd1.x * 32, da1 = (long long)sd1.y * 32;
        const float4 a00 = emb4[sa0 + g];
        const float4 b00 = emb4[da0 + g];
        const float4 a01 = emb4[sa0 + 16 + g];
        const float4 b01 = emb4[da0 + 16 + g];
        const float4 a10 = emb4[sa1 + g];
        const float4 b10 = emb4[da1 + g];
        const float4 a11 = emb4[sa1 + 16 + g];
        const float4 b11 = emb4[da1 + 16 + g];

        float p0 = a00.x*b00.x + a00.y*b00.y + a00.z*b00.z + a00.w*b00.w
                 + a01.x*b01.x + a01.y*b01.y + a01.z*b01.z + a01.w*b01.w;
        float p1 = a10.x*b10.x + a10.y*b10.y + a10.z*b10.z + a10.w*b10.w
                 + a11.x*b11.x + a11.y*b11.y + a11.z*b11.z + a11.w*b11.w;
        p0 += __shfl_xor(p0, 8);  p1 += __shfl_xor(p1, 8);
        p0 += __shfl_xor(p0, 4);  p1 += __shfl_xor(p1, 4);
        p0 += __shfl_xor(p0, 2);  p1 += __shfl_xor(p1, 2);
        p0 += __shfl_xor(p0, 1);  p1 += __shfl_xor(p1, 1);

        const float sc0 = p0 > 0.f ? p0 : kAlpha * p0;
        const float sc1 = p1 > 0.f ? p1 : kAlpha * p1;
        lmax = fmaxf(lmax, sc0);
        if (has1) lmax = fmaxf(lmax, sc1);
        if (g == 0) {
            scores[e0] = sc0;
            atomicAdd(&counts[sd0.x], 1);
            if (has1) { scores[e1] = sc1; atomicAdd(&counts[sd1.x], 1); }
        }
    }
    __shared__ float red[256];
    red[threadIdx.x] = lmax;
    __syncthreads();
    for (int s = blockDim.x >> 1; s > 0; s >>= 1) {
        if ((int)threadIdx.x < s) red[threadIdx.x] = fmaxf(red[threadIdx.x], red[threadIdx.x + s]);
        __syncthreads();
    }
    if (threadIdx.x == 0) atomicMaxF(gmax, red[0]);
}

__global__ void sumexp_kernel(const float* __restrict__ scores,
                              const float* __restrict__ gmax,
                              float* __restrict__ gsum) {
    const float m = *gmax;
    float acc = 0.0f;
    for (int i = blockIdx.x * blockDim.x + threadIdx.x; i < kEdges; i += gridDim.x * blockDim.x)
        acc += expf(scores[i] - m);
    __shared__ float red[256];
    red[threadIdx.x] = acc;
    __syncthreads();
    for (int s = blockDim.x >> 1; s > 0; s >>= 1) {
        if ((int)threadIdx.x < s) red[threadIdx.x] += red[threadIdx.x + s];
        __syncthreads();
    }
    if (threadIdx.x == 0) atomicAdd(gsum, red[0]);
}

__global__ void scanA_kernel(const int* __restrict__ counts, int* __restrict__ blocksum) {
    const int base = blockIdx.x * kScanChunk;
    int acc = 0;
    #pragma unroll
    for (int j = 0; j < 4; ++j) {
        const int i = base + 4 * (int)threadIdx.x + j;
        if (i < kNodes) acc += counts[i];
    }
    __shared__ int red[256];
    red[threadIdx.x] = acc;
    __syncthreads();
    for (int s = blockDim.x >> 1; s > 0; s >>= 1) {
        if ((int)threadIdx.x < s) red[threadIdx.x] += red[threadIdx.x + s];
        __syncthreads();
    }
    if (threadIdx.x == 0) blocksum[blockIdx.x] = red[0];
}

__global__ void scanB_kernel(int* __restrict__ blocksum) {
    __shared__ int lds[kScanBlocks];
    if ((int)threadIdx.x < kScanBlocks) lds[threadIdx.x] = blocksum[threadIdx.x];
    __syncthreads();
    if (threadIdx.x == 0) {
        int run = 0;
        for (int i = 0; i < kScanBlocks; ++i) { int t = lds[i]; lds[i] = run; run += t; }
    }
    __syncthreads();
    if ((int)threadIdx.x < kScanBlocks) blocksum[threadIdx.x] = lds[threadIdx.x];
}

__global__ void scanC_kernel(const int* __restrict__ counts,
                             const int* __restrict__ blocksum,
                             int* __restrict__ offsets,
                             int* __restrict__ cursor) {
    const int base = blockIdx.x * kScanChunk;
    const int lane = threadIdx.x & 63;
    const int wave = threadIdx.x >> 6;
    int c[4];
    int sum4 = 0;
    #pragma unroll
    for (int j = 0; j < 4; ++j) {
        const int i = base + 4 * (int)threadIdx.x + j;
        c[j] = (i < kNodes) ? counts[i] : 0;
        sum4 += c[j];
    }
    int incl = sum4;
    #pragma unroll
    for (int off = 1; off < 64; off <<= 1) {
        int v = __shfl_up(incl, off);
        if (lane >= off) incl += v;
    }
    __shared__ int waveSum[4];
    __shared__ int waveOff[4];
    if (lane == 63) waveSum[wave] = incl;
    __syncthreads();
    if (threadIdx.x == 0) {
        int run = 0;
        for (int w = 0; w < 4; ++w) { int t = waveSum[w]; waveOff[w] = run; run += t; }
    }
    __syncthreads();
    int excl = blocksum[blockIdx.x] + waveOff[wave] + (incl - sum4);
    #pragma unroll
    for (int j = 0; j < 4; ++j) {
        const int i = base + 4 * (int)threadIdx.x + j;
        if (i < kNodes) { offsets[i] = excl; cursor[i] = excl; }
        excl += c[j];
    }
}

// Pack (dst, normalized att weight) per CSR slot — removes exp + two loads
// from the gather's dependent chain.
__global__ void fill_kernel(const int2* __restrict__ rel2,
                            const float* __restrict__ scores,
                            const float* __restrict__ gmax,
                            const float* __restrict__ gsum,
                            int* __restrict__ cursor,
                            float2* __restrict__ meta) {
    const float m = *gmax;
    const float invs = 1.0f / *gsum;
    for (int e = blockIdx.x * blockDim.x + threadIdx.x; e < kEdges; e += gridDim.x * blockDim.x) {
        const int2 sd = rel2[e];
        const float w = expf(scores[e] - m) * invs;
        const int pos = atomicAdd(&cursor[sd.x], 1);
        meta[pos] = make_float2(__int_as_float(sd.y), w);
    }
}

// 32 lanes per node (float4 per lane), inner loop unrolled x2.
__global__ void gather_kernel(const float4* __restrict__ emb4,
                              const int* __restrict__ offsets,
                              const int* __restrict__ counts,
                              const float2* __restrict__ meta,
                              float4* __restrict__ out4) {
    const int g    = threadIdx.x & 31;
    const int node = (blockIdx.x * blockDim.x + threadIdx.x) >> 5;
    if (node >= kNodes) return;

    float4 acc = emb4[(long long)node * 32 + g];  // residual
    const int off = offsets[node];
    const int end = off + counts[node];

    int k = off;
    for (; k + 1 < end; k += 2) {
        const float2 m0 = meta[k];
        const float2 m1 = meta[k + 1];
        const float4 b0 = emb4[(long long)__float_as_int(m0.x) * 32 + g];
        const float4 b1 = emb4[(long long)__float_as_int(m1.x) * 32 + g];
        acc.x += m0.y * b0.x; acc.y += m0.y * b0.y; acc.z += m0.y * b0.z; acc.w += m0.y * b0.w;
        acc.x += m1.y * b1.x; acc.y += m1.y * b1.y; acc.z += m1.y * b1.z; acc.w += m1.y * b1.w;
    }
    if (k < end) {
        const float2 m0 = meta[k];
        const float4 b0 = emb4[(long long)__float_as_int(m0.x) * 32 + g];
        acc.x += m0.y * b0.x; acc.y += m0.y * b0.y; acc.z += m0.y * b0.z; acc.w += m0.y * b0.w;
    }
    out4[(long long)node * 32 + g] = acc;
}

extern "C" void kernel_launch(void* const* d_in, const int* in_sizes, int n_in,
                              void* d_out, int out_size, void* d_ws, size_t ws_size,
                              hipStream_t stream) {
    const float*  emb  = (const float*)d_in[0];
    const float4* emb4 = (const float4*)d_in[0];
    const int2*   rel2 = (const int2*)d_in[1];
    float4* out4 = (float4*)d_out;
    float* wsf = (float*)d_ws;
    int*   wsi = (int*)d_ws;

    float*  gmax     = wsf;
    float*  gsum     = wsf + 1;
    float*  scores   = wsf + kOffScores;
    int*    counts   = wsi + kOffCounts;
    int*    offsets  = wsi + kOffOffsets;
    int*    cursor   = wsi + kOffCursor;
    float2* meta     = (float2*)(wsf + kOffMeta);
    int*    blocksum = wsi + kOffBlockSum;
    (void)emb;

    hipLaunchKernelGGL(init_kernel, dim3(196), dim3(256), 0, stream, wsf, counts);
    hipLaunchKernelGGL(scores_max_count_kernel, dim3(2048), dim3(256), 0, stream,
                       emb4, rel2, scores, counts, gmax);
    hipLaunchKernelGGL(sumexp_kernel, dim3(1024), dim3(256), 0, stream,
                       scores, gmax, gsum);
    hipLaunchKernelGGL(scanA_kernel, dim3(kScanBlocks), dim3(256), 0, stream, counts, blocksum);
    hipLaunchKernelGGL(scanB_kernel, dim3(1), dim3(64), 0, stream, blocksum);
    hipLaunchKernelGGL(scanC_kernel, dim3(kScanBlocks), dim3(256), 0, stream,
                       counts, blocksum, offsets, cursor);
    hipLaunchKernelGGL(fill_kernel, dim3(1024), dim3(256), 0, stream,
                       rel2, scores, gmax, gsum, cursor, meta);
    hipLaunchKernelGGL(gather_kernel, dim3((kNodes + 7) / 8), dim3(256), 0, stream,
                       emb4, offsets, counts, meta, out4);
}